// Round 6
// baseline (804.881 us; speedup 1.0000x reference)
//
#include <hip/hip_runtime.h>

#define NR 4000
#define TS 60
#define DF 6
#define HD 64
#define MB 8   // rows per GRU block

typedef __attribute__((ext_vector_type(8))) short bf8_t;
typedef __attribute__((ext_vector_type(4))) float f32x4;

__device__ __forceinline__ float sigf(float x) { return 1.0f / (1.0f + __expf(-x)); }
__device__ __forceinline__ float tanhfast(float x) { return 1.0f - 2.0f / (1.0f + __expf(2.0f * x)); }

__device__ __forceinline__ unsigned short f2bf(float v) {
  union { float f; unsigned u; } x; x.f = v;
  unsigned r = (x.u + 0x7fffu + ((x.u >> 16) & 1u)) >> 16;
  return (unsigned short)r;
}
__device__ __forceinline__ float bf2f(unsigned short h) {
  union { unsigned u; float f; } y; y.u = ((unsigned)h) << 16; return y.f;
}
__device__ __forceinline__ void split8(const float* v, bf8_t& hi, bf8_t& lo) {
#pragma unroll
  for (int j = 0; j < 8; ++j) {
    unsigned short h = f2bf(v[j]);
    float rem = v[j] - bf2f(h);
    hi[j] = (short)h;
    lo[j] = (short)f2bf(rem);
  }
}

// ---------------------------------------------------------------------------
// Kernel 1: fused 2-layer GRU via split-bf16 MFMA. 500 blocks x 8 rows,
// 4 waves (wave w owns units [16w,16w+16)). Single-barrier skewed phase:
//   phase p: L0 MFMA (step p, uses a0=h0(p-1)) + L1 MFMA (step p-1, uses
//   a0 and a1=h1(p-2)) -> acts -> write h0(p),h1(p-1) to parity LDS ->
//   barrier -> cvt a0,a1.  61 phases, 1 barrier each.
// MFMA A-rows 8..15 duplicate rows 0..7 (8-row blocks on 16x16 shape).
// ---------------------------------------------------------------------------
__global__ __launch_bounds__(256, 2) void gru_mfma(
    const float* __restrict__ x,
    const float* __restrict__ Wih0, const float* __restrict__ Whh0,
    const float* __restrict__ bih0, const float* __restrict__ bhh0,
    const float* __restrict__ Wih1, const float* __restrict__ Whh1,
    const float* __restrict__ bih1, const float* __restrict__ bhh1,
    const float* __restrict__ Wac,
    float* __restrict__ xh_out, float* __restrict__ a_out, float* __restrict__ c_out) {
  __shared__ float xlds[MB * 362];
  __shared__ float h0b[2][MB][68];
  __shared__ float h1b[2][MB][68];
  __shared__ float red[2][4][MB];

  const int tid = threadIdx.x;
  const int w = tid >> 6;
  const int lane = tid & 63;
  const int lg = lane >> 4;
  const int lm = lane & 15;
  const int unit = w * 16 + lm;
  const int r0 = blockIdx.x * MB;

  for (int idx = tid; idx < MB * 360; idx += 256) {
    int rr = idx / 360, cc = idx - rr * 360;
    xlds[rr * 362 + cc] = x[(size_t)(r0 + rr) * 360 + cc];
  }

  // weight B-frags: wB[mat][gate][ktile][hi/lo]; B[k][n]=W[n][k]
  bf8_t wB[3][3][2][2];
  {
    const float* mats[3] = {Whh0, Wih1, Whh1};
#pragma unroll
    for (int m = 0; m < 3; ++m)
#pragma unroll
      for (int g = 0; g < 3; ++g)
#pragma unroll
        for (int kt = 0; kt < 2; ++kt) {
          const float* src = mats[m] + (size_t)(g * 64 + unit) * 64 + kt * 32 + 8 * lg;
          float v[8];
          *(float4*)&v[0] = *(const float4*)&src[0];
          *(float4*)&v[4] = *(const float4*)&src[4];
          split8(v, wB[m][g][kt][0], wB[m][g][kt][1]);
        }
  }
  float wih0g[3][DF];
#pragma unroll
  for (int g = 0; g < 3; ++g)
#pragma unroll
    for (int f = 0; f < DF; ++f)
      wih0g[g][f] = Wih0[(size_t)(g * 64 + unit) * DF + f];

  const float bi0r = bih0[unit], bi0z = bih0[64 + unit], bi0n = bih0[128 + unit];
  const float bh0r = bhh0[unit], bh0z = bhh0[64 + unit], bh0n = bhh0[128 + unit];
  const float c1R = bih1[unit] + bhh1[unit];
  const float c1Z = bih1[64 + unit] + bhh1[64 + unit];
  const float b1xn = bih1[128 + unit], b1hn = bhh1[128 + unit];

  bf8_t a0[2][2], a1[2][2];
  bf8_t zf = {};
#pragma unroll
  for (int kt = 0; kt < 2; ++kt)
#pragma unroll
    for (int h = 0; h < 2; ++h) { a0[kt][h] = zf; a1[kt][h] = zf; }
  float h0c[4] = {0.f, 0.f, 0.f, 0.f};
  float h1c[4] = {0.f, 0.f, 0.f, 0.f};

  __syncthreads();

#define MF(acc, A, B) acc = __builtin_amdgcn_mfma_f32_16x16x32_bf16(A, B, acc, 0, 0, 0)
#define MF3(acc, Af, Bf) do { \
    MF(acc, Af[0], Bf[0]); MF(acc, Af[0], Bf[1]); MF(acc, Af[1], Bf[0]); } while (0)

  for (int p = 0; p <= TS; ++p) {
    const bool doL0 = (p < TS);
    const bool doL1 = (p >= 1);
    f32x4 aR, aZ, aN;
    float xn0[4];
    if (doL0) {
#pragma unroll
      for (int i = 0; i < 4; ++i) {
        const int row = (4 * lg + i) & 7;
        const float* xb = &xlds[row * 362 + p];
        float sr = bi0r, sz = bi0z, sn = bi0n;
#pragma unroll
        for (int f = 0; f < DF; ++f) {
          float xv = xb[f * 60];
          sr = fmaf(wih0g[0][f], xv, sr);
          sz = fmaf(wih0g[1][f], xv, sz);
          sn = fmaf(wih0g[2][f], xv, sn);
        }
        aR[i] = sr + bh0r;
        aZ[i] = sz + bh0z;
        aN[i] = bh0n;
        xn0[i] = sn;
      }
#pragma unroll
      for (int kt = 0; kt < 2; ++kt) {
        MF3(aR, a0[kt], wB[0][0][kt]);
        MF3(aZ, a0[kt], wB[0][1][kt]);
        MF3(aN, a0[kt], wB[0][2][kt]);
      }
    }
    f32x4 R1, Z1, XN, HN;
    if (doL1) {
#pragma unroll
      for (int i = 0; i < 4; ++i) { R1[i] = c1R; Z1[i] = c1Z; XN[i] = b1xn; HN[i] = b1hn; }
#pragma unroll
      for (int kt = 0; kt < 2; ++kt) {
        MF3(R1, a0[kt], wB[1][0][kt]);   // xp1 = h0(p-1) @ Wih1^T
        MF3(Z1, a0[kt], wB[1][1][kt]);
        MF3(XN, a0[kt], wB[1][2][kt]);
        MF3(R1, a1[kt], wB[2][0][kt]);   // h1(p-2) @ Whh1^T
        MF3(Z1, a1[kt], wB[2][1][kt]);
        MF3(HN, a1[kt], wB[2][2][kt]);
      }
    }
    if (doL0) {
#pragma unroll
      for (int i = 0; i < 4; ++i) {
        float r = sigf(aR[i]);
        float z = sigf(aZ[i]);
        float n = tanhfast(xn0[i] + r * aN[i]);
        h0c[i] = n + z * (h0c[i] - n);
      }
      if (lg < 2) {
#pragma unroll
        for (int i = 0; i < 4; ++i) h0b[p & 1][4 * lg + i][unit] = h0c[i];
      }
    }
    if (doL1) {
#pragma unroll
      for (int i = 0; i < 4; ++i) {
        float r = sigf(R1[i]);
        float z = sigf(Z1[i]);
        float n = tanhfast(XN[i] + r * HN[i]);
        h1c[i] = n + z * (h1c[i] - n);
      }
      if (p < TS && lg < 2) {
#pragma unroll
        for (int i = 0; i < 4; ++i) h1b[p & 1][4 * lg + i][unit] = h1c[i];
      }
    }
    __syncthreads();
    if (p < TS) {
#pragma unroll
      for (int kt = 0; kt < 2; ++kt) {
        float v[8];
        *(float4*)&v[0] = *(const float4*)&h0b[p & 1][lm & 7][kt * 32 + 8 * lg];
        *(float4*)&v[4] = *(const float4*)&h0b[p & 1][lm & 7][kt * 32 + 8 * lg + 4];
        split8(v, a0[kt][0], a0[kt][1]);
      }
      if (p >= 1) {
#pragma unroll
        for (int kt = 0; kt < 2; ++kt) {
          float v[8];
          *(float4*)&v[0] = *(const float4*)&h1b[p & 1][lm & 7][kt * 32 + 8 * lg];
          *(float4*)&v[4] = *(const float4*)&h1b[p & 1][lm & 7][kt * 32 + 8 * lg + 4];
          split8(v, a1[kt][0], a1[kt][1]);
        }
      }
    }
  }
#undef MF3
#undef MF

  if (lg < 2) {
#pragma unroll
    for (int i = 0; i < 4; ++i)
      xh_out[(size_t)(r0 + 4 * lg + i) * HD + unit] = h1c[i];
  }
  const float WaU = Wac[unit], WcU = Wac[64 + unit];
#pragma unroll
  for (int i = 0; i < 4; ++i) {
    float av = h1c[i] * WaU, cv = h1c[i] * WcU;
#pragma unroll
    for (int off = 1; off < 16; off <<= 1) {
      av += __shfl_xor(av, off, 64);
      cv += __shfl_xor(cv, off, 64);
    }
    if (lm == 0 && lg < 2) {
      red[0][w][4 * lg + i] = av;
      red[1][w][4 * lg + i] = cv;
    }
  }
  __syncthreads();
  if (tid < MB) {
    a_out[r0 + tid] = red[0][0][tid] + red[0][1][tid] + red[0][2][tid] + red[0][3][tid];
    c_out[r0 + tid] = red[1][0][tid] + red[1][1][tid] + red[1][2][tid] + red[1][3][tid];
  }
}

// ---------------------------------------------------------------------------
// Kernel 2: masked graph attention + final FC. 500 blocks x 128 threads.
// Thread (rp=tid>>5, tk=tid&31) owns rows {i0+rp, i0+rp+4} x cols {2tk,2tk+1}
// -> each xhl read feeds 4 FMAs (2x LDS-BW reduction vs 1-row mapping).
// xhl padded [64][68] -> conflict-free stage writes, 2-way (free) reads.
// ---------------------------------------------------------------------------
#define NCH ((NR + 63) / 64)

__global__ __launch_bounds__(128) void attn_kernel(
    const float* __restrict__ rel,
    const float* __restrict__ xh,
    const float* __restrict__ aArr, const float* __restrict__ cArr,
    const float* __restrict__ bSc,
    const float* __restrict__ fcw,
    const float* __restrict__ fcb,
    float* __restrict__ pred) {
  __shared__ float xhl[64][68];   // 17.4KB padded
  __shared__ float pbuf[8][64];
  __shared__ float clA[NR];

  const int tid = threadIdx.x;
  const int rp = tid >> 5;
  const int tk = tid & 31;
  const int i0 = blockIdx.x * 8;
  const int iA = i0 + rp, iB = i0 + rp + 4;
  const float bb = bSc[0];
  const float aibA = aArr[iA] + bb;
  const float aibB = aArr[iB] + bb;

  for (int t = tid; t < NR; t += 128) clA[t] = cArr[t];

  float prA[6], prB[6];
  {
    const int j = 2 * tk;
    const float* rpa = rel + (size_t)iA * (3 * NR) + (size_t)j * 3;
    const float* rpb = rel + (size_t)iB * (3 * NR) + (size_t)j * 3;
#pragma unroll
    for (int e = 0; e < 6; ++e) { prA[e] = rpa[e]; prB[e] = rpb[e]; }
  }

  float mA = -3.0e38f, sA = 0.f, mB = -3.0e38f, sB = 0.f;
  float accA0 = 0.f, accA1 = 0.f, accB0 = 0.f, accB1 = 0.f;

  for (int c = 0; c < NCH; ++c) {
    const int j0 = c * 64;
    __syncthreads();
    // stage xh chunk: 8 x float4 per thread, conflict-free padded layout
#pragma unroll
    for (int it = 0; it < 8; ++it) {
      const int slot = it * 128 + tid;
      const int row = slot >> 4, seg = slot & 15;
      const int j = j0 + row;
      float4 v = {0.f, 0.f, 0.f, 0.f};
      if (j < NR) v = *(const float4*)(xh + (size_t)j * 64 + seg * 4);
      *(float4*)&xhl[row][seg * 4] = v;
    }

    // scores from prefetched rel regs
    const int jb = j0 + 2 * tk;
    const bool ok = (jb < NR);
    const int jbc = ok ? jb : (NR - 2);
    const float cl0 = clA[jbc], cl1 = clA[jbc + 1];
    float msA0 = prA[0] + prA[1] + prA[2], msA1 = prA[3] + prA[4] + prA[5];
    float msB0 = prB[0] + prB[1] + prB[2], msB1 = prB[3] + prB[4] + prB[5];
    float wA0 = aibA + cl0, wA1 = aibA + cl1;
    float wB0 = aibB + cl0, wB1 = aibB + cl1;
    wA0 = (wA0 > 0.f) ? wA0 : 0.01f * wA0;
    wA1 = (wA1 > 0.f) ? wA1 : 0.01f * wA1;
    wB0 = (wB0 > 0.f) ? wB0 : 0.01f * wB0;
    wB1 = (wB1 > 0.f) ? wB1 : 0.01f * wB1;
    float vA0 = (!ok) ? -3.0e37f : ((msA0 == 0.f) ? -1.0e6f : msA0 * wA0);
    float vA1 = (!ok) ? -3.0e37f : ((msA1 == 0.f) ? -1.0e6f : msA1 * wA1);
    float vB0 = (!ok) ? -3.0e37f : ((msB0 == 0.f) ? -1.0e6f : msB0 * wB0);
    float vB1 = (!ok) ? -3.0e37f : ((msB1 == 0.f) ? -1.0e6f : msB1 * wB1);

    // prefetch next chunk
    if (c + 1 < NCH) {
      const int jn = j0 + 64 + 2 * tk;
      if (jn < NR) {
        const float* rpa = rel + (size_t)iA * (3 * NR) + (size_t)jn * 3;
        const float* rpb = rel + (size_t)iB * (3 * NR) + (size_t)jn * 3;
#pragma unroll
        for (int e = 0; e < 6; ++e) { prA[e] = rpa[e]; prB[e] = rpb[e]; }
      }
    }

    // online softmax (per row, across 32 tk lanes)
    float lmA = fmaxf(vA0, vA1), lmB = fmaxf(vB0, vB1);
#pragma unroll
    for (int off = 16; off; off >>= 1) {
      lmA = fmaxf(lmA, __shfl_xor(lmA, off, 32));
      lmB = fmaxf(lmB, __shfl_xor(lmB, off, 32));
    }
    const float mnA = fmaxf(mA, lmA), mnB = fmaxf(mB, lmB);
    const float fA = __expf(mA - mnA), fB = __expf(mB - mnB);
    const float pA0 = __expf(vA0 - mnA), pA1 = __expf(vA1 - mnA);
    const float pB0 = __expf(vB0 - mnB), pB1 = __expf(vB1 - mnB);
    float lsA = pA0 + pA1, lsB = pB0 + pB1;
#pragma unroll
    for (int off = 16; off; off >>= 1) {
      lsA += __shfl_xor(lsA, off, 32);
      lsB += __shfl_xor(lsB, off, 32);
    }
    sA = sA * fA + lsA;
    sB = sB * fB + lsB;
    accA0 *= fA; accA1 *= fA; accB0 *= fB; accB1 *= fB;
    mA = mnA; mB = mnB;
    pbuf[rp][2 * tk] = pA0;
    pbuf[rp][2 * tk + 1] = pA1;
    pbuf[rp + 4][2 * tk] = pB0;
    pbuf[rp + 4][2 * tk + 1] = pB1;  // written & read by same half-wave

    __syncthreads();  // xhl ready

#pragma unroll 4
    for (int j4 = 0; j4 < 16; ++j4) {
      float4 pvA = *(const float4*)&pbuf[rp][4 * j4];
      float4 pvB = *(const float4*)&pbuf[rp + 4][4 * j4];
      float2 x0 = *(const float2*)&xhl[4 * j4 + 0][2 * tk];
      float2 x1 = *(const float2*)&xhl[4 * j4 + 1][2 * tk];
      float2 x2 = *(const float2*)&xhl[4 * j4 + 2][2 * tk];
      float2 x3 = *(const float2*)&xhl[4 * j4 + 3][2 * tk];
      accA0 = fmaf(pvA.x, x0.x, accA0); accA1 = fmaf(pvA.x, x0.y, accA1);
      accB0 = fmaf(pvB.x, x0.x, accB0); accB1 = fmaf(pvB.x, x0.y, accB1);
      accA0 = fmaf(pvA.y, x1.x, accA0); accA1 = fmaf(pvA.y, x1.y, accA1);
      accB0 = fmaf(pvB.y, x1.x, accB0); accB1 = fmaf(pvB.y, x1.y, accB1);
      accA0 = fmaf(pvA.z, x2.x, accA0); accA1 = fmaf(pvA.z, x2.y, accA1);
      accB0 = fmaf(pvB.z, x2.x, accB0); accB1 = fmaf(pvB.z, x2.y, accB1);
      accA0 = fmaf(pvA.w, x3.x, accA0); accA1 = fmaf(pvA.w, x3.y, accA1);
      accB0 = fmaf(pvB.w, x3.x, accB0); accB1 = fmaf(pvB.w, x3.y, accB1);
    }
  }

  // epilogue: normalize + fc, per owned row
  {
    const float invA = 1.0f / sA, invB = 1.0f / sB;
    const float oA0 = accA0 * invA, oA1 = accA1 * invA;
    const float oB0 = accB0 * invB, oB1 = accB1 * invB;
    const float w0 = fcw[2 * tk], w1 = fcw[2 * tk + 1];
    const float w2 = fcw[64 + 2 * tk], w3 = fcw[64 + 2 * tk + 1];
    float2 xiA = *(const float2*)(xh + (size_t)iA * 64 + 2 * tk);
    float2 xiB = *(const float2*)(xh + (size_t)iB * 64 + 2 * tk);
    float pa = w0 * xiA.x + w1 * xiA.y + w2 * oA0 + w3 * oA1;
    float pb = w0 * xiB.x + w1 * xiB.y + w2 * oB0 + w3 * oB1;
#pragma unroll
    for (int off = 16; off; off >>= 1) {
      pa += __shfl_xor(pa, off, 32);
      pb += __shfl_xor(pb, off, 32);
    }
    if (tk == 0) {
      pred[iA] = pa + fcb[0];
      pred[iB] = pb + fcb[0];
    }
  }
}

extern "C" void kernel_launch(void* const* d_in, const int* in_sizes, int n_in,
                              void* d_out, int out_size, void* d_ws, size_t ws_size,
                              hipStream_t stream) {
  const float* x    = (const float*)d_in[0];
  const float* rel  = (const float*)d_in[1];
  const float* Wih0 = (const float*)d_in[2];
  const float* Whh0 = (const float*)d_in[3];
  const float* bih0 = (const float*)d_in[4];
  const float* bhh0 = (const float*)d_in[5];
  const float* Wih1 = (const float*)d_in[6];
  const float* Whh1 = (const float*)d_in[7];
  const float* bih1 = (const float*)d_in[8];
  const float* bhh1 = (const float*)d_in[9];
  const float* Wac  = (const float*)d_in[10];
  const float* bSc  = (const float*)d_in[11];
  const float* fcw  = (const float*)d_in[12];
  const float* fcb  = (const float*)d_in[13];

  float* xh = (float*)d_ws;
  float* aA = xh + (size_t)NR * HD;
  float* cA = aA + NR;
  float* pred = (float*)d_out;

  gru_mfma<<<NR / MB, 256, 0, stream>>>(x, Wih0, Whh0, bih0, bhh0, Wih1, Whh1,
                                        bih1, bhh1, Wac, xh, aA, cA);
  attn_kernel<<<NR / 8, 128, 0, stream>>>(rel, xh, aA, cA, bSc, fcw, fcb, pred);
}

// Round 7
// 256.551 us; speedup vs baseline: 3.1373x; 3.1373x over previous
//
#include <hip/hip_runtime.h>

#define NR 4000
#define TS 60
#define DF 6
#define HD 64
#define MB 16    // rows per GRU block
#define JSL 1024 // attn j-slice per partial block
#define NSPLIT 4

typedef __attribute__((ext_vector_type(8))) short bf8_t;
typedef __attribute__((ext_vector_type(4))) float f32x4;

__device__ __forceinline__ float sigf(float x) { return 1.0f / (1.0f + __expf(-x)); }
__device__ __forceinline__ float tanhfast(float x) { return 1.0f - 2.0f / (1.0f + __expf(2.0f * x)); }

__device__ __forceinline__ unsigned short f2bf(float v) {
  union { float f; unsigned u; } x; x.f = v;
  unsigned r = (x.u + 0x7fffu + ((x.u >> 16) & 1u)) >> 16;
  return (unsigned short)r;
}
__device__ __forceinline__ float bf2f(unsigned short h) {
  union { unsigned u; float f; } y; y.u = ((unsigned)h) << 16; return y.f;
}
__device__ __forceinline__ void split8(const float* v, bf8_t& hi, bf8_t& lo) {
#pragma unroll
  for (int j = 0; j < 8; ++j) {
    unsigned short h = f2bf(v[j]);
    float rem = v[j] - bf2f(h);
    hi[j] = (short)h;
    lo[j] = (short)f2bf(rem);
  }
}

// ---------------------------------------------------------------------------
// Kernel 1: fused 2-layer GRU via split-bf16 MFMA. 250 blocks x 16 rows,
// 4 waves (wave w owns units [16w,16w+16)). Skewed single-barrier phase:
//   phase p: L0 MFMA (step p, uses a0=h0(p-1)) + L1 MFMA (step p-1, uses
//   a0 and a1=h1(p-2)) -> acts -> write h0(p),h1(p-1) to parity LDS ->
//   barrier -> cvt a0,a1.  61 phases, 1 barrier each.
// __launch_bounds__(256,1): 512-reg budget so the 144 weight-frag regs stay
// resident (AGPR/VGPR unified) -- (256,2) spills them to scratch (round 6:
// 1.1 GB FETCH, 600us).
// ---------------------------------------------------------------------------
__global__ __launch_bounds__(256, 1) void gru_mfma(
    const float* __restrict__ x,
    const float* __restrict__ Wih0, const float* __restrict__ Whh0,
    const float* __restrict__ bih0, const float* __restrict__ bhh0,
    const float* __restrict__ Wih1, const float* __restrict__ Whh1,
    const float* __restrict__ bih1, const float* __restrict__ bhh1,
    const float* __restrict__ Wac,
    float* __restrict__ xh_out, float* __restrict__ a_out, float* __restrict__ c_out) {
  __shared__ float xlds[MB * 362];
  __shared__ float h0b[2][MB][68];
  __shared__ float h1b[2][MB][68];
  __shared__ float red[2][4][MB];

  const int tid = threadIdx.x;
  const int w = tid >> 6;
  const int lane = tid & 63;
  const int lg = lane >> 4;
  const int lm = lane & 15;
  const int unit = w * 16 + lm;
  const int r0 = blockIdx.x * MB;

  for (int idx = tid; idx < MB * 360; idx += 256) {
    int rr = idx / 360, cc = idx - rr * 360;
    xlds[rr * 362 + cc] = x[(size_t)(r0 + rr) * 360 + cc];
  }

  // weight B-frags: wB[mat][gate][ktile][hi/lo]; B[k][n]=W[n][k]
  bf8_t wB[3][3][2][2];
  {
    const float* mats[3] = {Whh0, Wih1, Whh1};
#pragma unroll
    for (int m = 0; m < 3; ++m)
#pragma unroll
      for (int g = 0; g < 3; ++g)
#pragma unroll
        for (int kt = 0; kt < 2; ++kt) {
          const float* src = mats[m] + (size_t)(g * 64 + unit) * 64 + kt * 32 + 8 * lg;
          float v[8];
          *(float4*)&v[0] = *(const float4*)&src[0];
          *(float4*)&v[4] = *(const float4*)&src[4];
          split8(v, wB[m][g][kt][0], wB[m][g][kt][1]);
        }
  }
  float wih0g[3][DF];
#pragma unroll
  for (int g = 0; g < 3; ++g)
#pragma unroll
    for (int f = 0; f < DF; ++f)
      wih0g[g][f] = Wih0[(size_t)(g * 64 + unit) * DF + f];

  const float bi0r = bih0[unit], bi0z = bih0[64 + unit], bi0n = bih0[128 + unit];
  const float bh0r = bhh0[unit], bh0z = bhh0[64 + unit], bh0n = bhh0[128 + unit];
  const float c1R = bih1[unit] + bhh1[unit];
  const float c1Z = bih1[64 + unit] + bhh1[64 + unit];
  const float b1xn = bih1[128 + unit], b1hn = bhh1[128 + unit];

  bf8_t a0[2][2], a1[2][2];
  bf8_t zf = {};
#pragma unroll
  for (int kt = 0; kt < 2; ++kt)
#pragma unroll
    for (int h = 0; h < 2; ++h) { a0[kt][h] = zf; a1[kt][h] = zf; }
  float h0c[4] = {0.f, 0.f, 0.f, 0.f};
  float h1c[4] = {0.f, 0.f, 0.f, 0.f};

  __syncthreads();

#define MF(acc, A, B) acc = __builtin_amdgcn_mfma_f32_16x16x32_bf16(A, B, acc, 0, 0, 0)
#define MF3(acc, Af, Bf) do { \
    MF(acc, Af[0], Bf[0]); MF(acc, Af[0], Bf[1]); MF(acc, Af[1], Bf[0]); } while (0)

  for (int p = 0; p <= TS; ++p) {
    const bool doL0 = (p < TS);
    const bool doL1 = (p >= 1);
    f32x4 aR, aZ, aN;
    float xn0[4];
    if (doL0) {
#pragma unroll
      for (int i = 0; i < 4; ++i) {
        const int row = 4 * lg + i;
        const float* xb = &xlds[row * 362 + p];
        float sr = bi0r, sz = bi0z, sn = bi0n;
#pragma unroll
        for (int f = 0; f < DF; ++f) {
          float xv = xb[f * 60];
          sr = fmaf(wih0g[0][f], xv, sr);
          sz = fmaf(wih0g[1][f], xv, sz);
          sn = fmaf(wih0g[2][f], xv, sn);
        }
        aR[i] = sr + bh0r;
        aZ[i] = sz + bh0z;
        aN[i] = bh0n;
        xn0[i] = sn;
      }
#pragma unroll
      for (int kt = 0; kt < 2; ++kt) {
        MF3(aR, a0[kt], wB[0][0][kt]);
        MF3(aZ, a0[kt], wB[0][1][kt]);
        MF3(aN, a0[kt], wB[0][2][kt]);
      }
    }
    f32x4 R1, Z1, XN, HN;
    if (doL1) {
#pragma unroll
      for (int i = 0; i < 4; ++i) { R1[i] = c1R; Z1[i] = c1Z; XN[i] = b1xn; HN[i] = b1hn; }
#pragma unroll
      for (int kt = 0; kt < 2; ++kt) {
        MF3(R1, a0[kt], wB[1][0][kt]);   // xp1 = h0(p-1) @ Wih1^T
        MF3(Z1, a0[kt], wB[1][1][kt]);
        MF3(XN, a0[kt], wB[1][2][kt]);
        MF3(R1, a1[kt], wB[2][0][kt]);   // h1(p-2) @ Whh1^T
        MF3(Z1, a1[kt], wB[2][1][kt]);
        MF3(HN, a1[kt], wB[2][2][kt]);
      }
    }
    if (doL0) {
#pragma unroll
      for (int i = 0; i < 4; ++i) {
        float r = sigf(aR[i]);
        float z = sigf(aZ[i]);
        float n = tanhfast(xn0[i] + r * aN[i]);
        h0c[i] = n + z * (h0c[i] - n);
        h0b[p & 1][4 * lg + i][unit] = h0c[i];
      }
    }
    if (doL1) {
#pragma unroll
      for (int i = 0; i < 4; ++i) {
        float r = sigf(R1[i]);
        float z = sigf(Z1[i]);
        float n = tanhfast(XN[i] + r * HN[i]);
        h1c[i] = n + z * (h1c[i] - n);
      }
      if (p < TS) {
#pragma unroll
        for (int i = 0; i < 4; ++i) h1b[p & 1][4 * lg + i][unit] = h1c[i];
      }
    }
    __syncthreads();
    if (p < TS) {
#pragma unroll
      for (int kt = 0; kt < 2; ++kt) {
        float v[8];
        *(float4*)&v[0] = *(const float4*)&h0b[p & 1][lm][kt * 32 + 8 * lg];
        *(float4*)&v[4] = *(const float4*)&h0b[p & 1][lm][kt * 32 + 8 * lg + 4];
        split8(v, a0[kt][0], a0[kt][1]);
      }
      if (p >= 1) {
#pragma unroll
        for (int kt = 0; kt < 2; ++kt) {
          float v[8];
          *(float4*)&v[0] = *(const float4*)&h1b[p & 1][lm][kt * 32 + 8 * lg];
          *(float4*)&v[4] = *(const float4*)&h1b[p & 1][lm][kt * 32 + 8 * lg + 4];
          split8(v, a1[kt][0], a1[kt][1]);
        }
      }
    }
  }
#undef MF3
#undef MF

#pragma unroll
  for (int i = 0; i < 4; ++i)
    xh_out[(size_t)(r0 + 4 * lg + i) * HD + unit] = h1c[i];

  const float WaU = Wac[unit], WcU = Wac[64 + unit];
#pragma unroll
  for (int i = 0; i < 4; ++i) {
    float av = h1c[i] * WaU, cv = h1c[i] * WcU;
#pragma unroll
    for (int off = 1; off < 16; off <<= 1) {
      av += __shfl_xor(av, off, 64);
      cv += __shfl_xor(cv, off, 64);
    }
    if (lm == 0) {
      red[0][w][4 * lg + i] = av;
      red[1][w][4 * lg + i] = cv;
    }
  }
  __syncthreads();
  if (tid < MB) {
    a_out[r0 + tid] = red[0][0][tid] + red[0][1][tid] + red[0][2][tid] + red[0][3][tid];
    c_out[r0 + tid] = red[1][0][tid] + red[1][1][tid] + red[1][2][tid] + red[1][3][tid];
  }
}

// ---------------------------------------------------------------------------
// Kernel 2a: attention PARTIAL (flash-decoding j-split x4). 2000 blocks x 256.
// Block (ib, js) handles rows ib*8..+8, j in [js*1024, min(4000,(js+1)*1024)).
// Writes per row: {m, s, acc[64]} (unnormalized online-softmax state).
// ---------------------------------------------------------------------------
__global__ __launch_bounds__(256) void attn_part(
    const float* __restrict__ rel,
    const float* __restrict__ xh,
    const float* __restrict__ aArr, const float* __restrict__ cArr,
    const float* __restrict__ bSc,
    float* __restrict__ part) {   // [2000][8][66]
  __shared__ float xhl[64][68];
  __shared__ float pbuf[8][64];
  __shared__ float cls[JSL];

  const int tid = threadIdx.x;
  const int il = tid >> 5;
  const int tk = tid & 31;
  const int bx = blockIdx.x;
  const int ib = bx >> 2;
  const int js = bx & 3;
  const int i = ib * 8 + il;
  const int jbeg = js * JSL;
  const int jend = (jbeg + JSL < NR) ? (jbeg + JSL) : NR;
  const int nch = (jend - jbeg + 63) >> 6;
  const float aib = aArr[i] + bSc[0];

  for (int t = tid; t < JSL; t += 256)
    cls[t] = (jbeg + t < NR) ? cArr[jbeg + t] : 0.f;

  float pr[6];
  {
    const float* rp = rel + (size_t)i * (3 * NR) + (size_t)(jbeg + 2 * tk) * 3;
#pragma unroll
    for (int e = 0; e < 6; ++e) pr[e] = rp[e];
  }

  float m = -3.0e38f, s = 0.f, acc0 = 0.f, acc1 = 0.f;

  for (int c = 0; c < nch; ++c) {
    const int j0 = jbeg + c * 64;
    __syncthreads();
    // stage xh chunk (padded rows -> conflict-free)
    {
      const int jj = tid >> 2, seg = tid & 3;
      const int j = j0 + jj;
      if (j < NR) {
        const float4* src = (const float4*)(xh + (size_t)j * 64 + seg * 16);
#pragma unroll
        for (int q = 0; q < 4; ++q) *(float4*)&xhl[jj][seg * 16 + 4 * q] = src[q];
      } else {
        float4 z = {0.f, 0.f, 0.f, 0.f};
#pragma unroll
        for (int q = 0; q < 4; ++q) *(float4*)&xhl[jj][seg * 16 + 4 * q] = z;
      }
    }

    const int jb = j0 + 2 * tk;
    const bool ok = (jb < jend);
    const int ci = c * 64 + 2 * tk;
    const float cl0 = cls[ci], cl1 = cls[ci + 1];
    float msum0 = pr[0] + pr[1] + pr[2];
    float msum1 = pr[3] + pr[4] + pr[5];
    float w0 = aib + cl0, w1 = aib + cl1;
    w0 = (w0 > 0.f) ? w0 : 0.01f * w0;
    w1 = (w1 > 0.f) ? w1 : 0.01f * w1;
    float vwa0 = (!ok) ? -3.0e37f : ((msum0 == 0.f) ? -1.0e6f : msum0 * w0);
    float vwa1 = (!ok) ? -3.0e37f : ((msum1 == 0.f) ? -1.0e6f : msum1 * w1);

    if (c + 1 < nch) {
      const int jn = j0 + 64 + 2 * tk;
      if (jn < jend) {
        const float* rp = rel + (size_t)i * (3 * NR) + (size_t)jn * 3;
#pragma unroll
        for (int e = 0; e < 6; ++e) pr[e] = rp[e];
      }
    }

    float lm = fmaxf(vwa0, vwa1);
#pragma unroll
    for (int off = 16; off; off >>= 1) lm = fmaxf(lm, __shfl_xor(lm, off, 32));
    const float mn = fmaxf(m, lm);
    const float f = __expf(m - mn);
    const float p0 = __expf(vwa0 - mn);
    const float p1 = __expf(vwa1 - mn);
    float ls = p0 + p1;
#pragma unroll
    for (int off = 16; off; off >>= 1) ls += __shfl_xor(ls, off, 32);
    s = s * f + ls;
    acc0 *= f;
    acc1 *= f;
    m = mn;
    pbuf[il][2 * tk] = p0;
    pbuf[il][2 * tk + 1] = p1;  // same half-wave writes & reads: lockstep-safe

    __syncthreads();

#pragma unroll 4
    for (int j4 = 0; j4 < 16; ++j4) {
      float4 pv = *(const float4*)&pbuf[il][4 * j4];
      float2 x0 = *(const float2*)&xhl[4 * j4 + 0][2 * tk];
      float2 x1 = *(const float2*)&xhl[4 * j4 + 1][2 * tk];
      float2 x2 = *(const float2*)&xhl[4 * j4 + 2][2 * tk];
      float2 x3 = *(const float2*)&xhl[4 * j4 + 3][2 * tk];
      acc0 = fmaf(pv.x, x0.x, acc0); acc1 = fmaf(pv.x, x0.y, acc1);
      acc0 = fmaf(pv.y, x1.x, acc0); acc1 = fmaf(pv.y, x1.y, acc1);
      acc0 = fmaf(pv.z, x2.x, acc0); acc1 = fmaf(pv.z, x2.y, acc1);
      acc0 = fmaf(pv.w, x3.x, acc0); acc1 = fmaf(pv.w, x3.y, acc1);
    }
  }

  float* base = part + ((size_t)bx * 8 + il) * 66;
  if (tk == 0) { base[0] = m; base[1] = s; }
  base[2 + 2 * tk] = acc0;
  base[3 + 2 * tk] = acc1;
}

// ---------------------------------------------------------------------------
// Kernel 2b: combine partials + final FC. 1000 blocks x 256 (4 rows/block,
// 64 lanes per row). o = (sum_k w_k acc_k) / (sum_k w_k s_k), w_k=exp(m_k-m*).
// pred = fcw[0:64].x_hidden + fcw[64:128].o + fcb.
// ---------------------------------------------------------------------------
__global__ __launch_bounds__(256) void attn_combine(
    const float* __restrict__ part,
    const float* __restrict__ xh,
    const float* __restrict__ fcw, const float* __restrict__ fcb,
    float* __restrict__ pred) {
  const int tid = threadIdx.x;
  const int r = blockIdx.x * 4 + (tid >> 6);
  const int lane = tid & 63;
  const int ib = r >> 3, il = r & 7;

  float mk[NSPLIT], sk[NSPLIT];
  float mstar = -3.0e38f;
#pragma unroll
  for (int k = 0; k < NSPLIT; ++k) {
    const float* b = part + ((size_t)(ib * 4 + k) * 8 + il) * 66;
    mk[k] = b[0];
    sk[k] = b[1];
    mstar = fmaxf(mstar, mk[k]);
  }
  float sstar = 0.f, onum = 0.f;
#pragma unroll
  for (int k = 0; k < NSPLIT; ++k) {
    const float wk = __expf(mk[k] - mstar);
    sstar = fmaf(wk, sk[k], sstar);
    const float* b = part + ((size_t)(ib * 4 + k) * 8 + il) * 66;
    onum = fmaf(wk, b[2 + lane], onum);
  }
  const float o = onum / sstar;
  float p = fcw[lane] * xh[(size_t)r * HD + lane] + fcw[64 + lane] * o;
#pragma unroll
  for (int off = 32; off; off >>= 1) p += __shfl_xor(p, off, 64);
  if (lane == 0) pred[r] = p + fcb[0];
}

extern "C" void kernel_launch(void* const* d_in, const int* in_sizes, int n_in,
                              void* d_out, int out_size, void* d_ws, size_t ws_size,
                              hipStream_t stream) {
  const float* x    = (const float*)d_in[0];
  const float* rel  = (const float*)d_in[1];
  const float* Wih0 = (const float*)d_in[2];
  const float* Whh0 = (const float*)d_in[3];
  const float* bih0 = (const float*)d_in[4];
  const float* bhh0 = (const float*)d_in[5];
  const float* Wih1 = (const float*)d_in[6];
  const float* Whh1 = (const float*)d_in[7];
  const float* bih1 = (const float*)d_in[8];
  const float* bhh1 = (const float*)d_in[9];
  const float* Wac  = (const float*)d_in[10];
  const float* bSc  = (const float*)d_in[11];
  const float* fcw  = (const float*)d_in[12];
  const float* fcb  = (const float*)d_in[13];

  float* xh   = (float*)d_ws;              // 256000 floats
  float* aA   = xh + (size_t)NR * HD;      // 4000
  float* cA   = aA + NR;                   // 4000
  float* part = cA + NR;                   // 2000*8*66 = 1,056,000 floats
  float* pred = (float*)d_out;

  gru_mfma<<<NR / MB, 256, 0, stream>>>(x, Wih0, Whh0, bih0, bhh0, Wih1, Whh1,
                                        bih1, bhh1, Wac, xh, aA, cA);
  attn_part<<<(NR / 8) * NSPLIT, 256, 0, stream>>>(rel, xh, aA, cA, bSc, part);
  attn_combine<<<NR / 4, 256, 0, stream>>>(part, xh, fcw, fcb, pred);
}

// Round 8
// 226.490 us; speedup vs baseline: 3.5537x; 1.1327x over previous
//
#include <hip/hip_runtime.h>

#define NR 4000
#define TS 60
#define DF 6
#define HD 64
#define MB 16    // rows per GRU block

typedef __attribute__((ext_vector_type(8))) short bf8_t;
typedef __attribute__((ext_vector_type(4))) short bf4_t;
typedef __attribute__((ext_vector_type(4))) float f32x4;

__device__ __forceinline__ float sigf(float x) { return 1.0f / (1.0f + __expf(-x)); }
__device__ __forceinline__ float tanhfast(float x) { return 1.0f - 2.0f / (1.0f + __expf(2.0f * x)); }

__device__ __forceinline__ unsigned short f2bf(float v) {  // RTN (weights, one-time)
  union { float f; unsigned u; } x; x.f = v;
  unsigned r = (x.u + 0x7fffu + ((x.u >> 16) & 1u)) >> 16;
  return (unsigned short)r;
}
__device__ __forceinline__ float bf2f(unsigned short h) {
  union { unsigned u; float f; } y; y.u = ((unsigned)h) << 16; return y.f;
}
__device__ __forceinline__ void split8(const float* v, bf8_t& hi, bf8_t& lo) {
#pragma unroll
  for (int j = 0; j < 8; ++j) {
    unsigned short h = f2bf(v[j]);
    float rem = v[j] - bf2f(h);
    hi[j] = (short)h;
    lo[j] = (short)f2bf(rem);
  }
}

// ---------------------------------------------------------------------------
// Kernel 1: fused 2-layer GRU via split-bf16 MFMA. 250 blocks x 16 rows,
// 4 waves. Skewed single-barrier phase (61 phases):
//   phase p: L0 MFMA(step p, a0=h0(p-1)) + L1 MFMA(step p-1, a0, a1=h1(p-2))
//   -> acts -> PRODUCER-SIDE hi/lo bf16 split -> ds_write_b16 to parity LDS
//   -> barrier -> consumers build a0/a1 frags with raw ds_read_b64 pairs
//   (zero conversion VALU -- round 7 spent ~440 VALU insts/phase on split8).
// h split: hi=trunc(f32), lo=bf16(f32-hi): combined rel err ~2^-16.
// __launch_bounds__(256,1): weight frags (144 AGPRs) must stay resident.
// ---------------------------------------------------------------------------
__global__ __launch_bounds__(256, 1) void gru_mfma(
    const float* __restrict__ x,
    const float* __restrict__ Wih0, const float* __restrict__ Whh0,
    const float* __restrict__ bih0, const float* __restrict__ bhh0,
    const float* __restrict__ Wih1, const float* __restrict__ Whh1,
    const float* __restrict__ bih1, const float* __restrict__ bhh1,
    const float* __restrict__ Wac,
    float* __restrict__ xh_out, float* __restrict__ a_out, float* __restrict__ c_out) {
  __shared__ float xldsT[TS][MB][12];        // [t][row][feat], 46KB, xp0 reads broadcast
  __shared__ unsigned short h0hiL[2][16][76]; // stride 76 shorts=152B: <=4-way frag reads
  __shared__ unsigned short h0loL[2][16][76];
  __shared__ unsigned short h1hiL[2][16][76];
  __shared__ unsigned short h1loL[2][16][76];
  __shared__ float red[2][4][MB];

  const int tid = threadIdx.x;
  const int w = tid >> 6;
  const int lane = tid & 63;
  const int lg = lane >> 4;
  const int lm = lane & 15;
  const int unit = w * 16 + lm;
  const int r0 = blockIdx.x * MB;

  // stage x rows, transposed to [t][row][f] (coalesced global reads)
  for (int idx = tid; idx < MB * 360; idx += 256) {
    int rr = idx / 360, cc = idx - rr * 360;
    int f = cc / 60, t = cc - f * 60;
    xldsT[t][rr][f] = x[(size_t)r0 * 360 + idx];
  }

  // weight B-frags (one-time RTN split): wB[mat][gate][ktile][hi/lo]; B[k][n]=W[n][k]
  bf8_t wB[3][3][2][2];
  {
    const float* mats[3] = {Whh0, Wih1, Whh1};
#pragma unroll
    for (int m = 0; m < 3; ++m)
#pragma unroll
      for (int g = 0; g < 3; ++g)
#pragma unroll
        for (int kt = 0; kt < 2; ++kt) {
          const float* src = mats[m] + (size_t)(g * 64 + unit) * 64 + kt * 32 + 8 * lg;
          float v[8];
          *(float4*)&v[0] = *(const float4*)&src[0];
          *(float4*)&v[4] = *(const float4*)&src[4];
          split8(v, wB[m][g][kt][0], wB[m][g][kt][1]);
        }
  }
  float wih0g[3][DF];
#pragma unroll
  for (int g = 0; g < 3; ++g)
#pragma unroll
    for (int f = 0; f < DF; ++f)
      wih0g[g][f] = Wih0[(size_t)(g * 64 + unit) * DF + f];

  const float bi0r = bih0[unit], bi0z = bih0[64 + unit], bi0n = bih0[128 + unit];
  const float bh0r = bhh0[unit], bh0z = bhh0[64 + unit], bh0n = bhh0[128 + unit];
  const float c1R = bih1[unit] + bhh1[unit];
  const float c1Z = bih1[64 + unit] + bhh1[64 + unit];
  const float b1xn = bih1[128 + unit], b1hn = bhh1[128 + unit];

  bf8_t a0[2][2], a1[2][2];
  bf8_t zf = {};
#pragma unroll
  for (int kt = 0; kt < 2; ++kt)
#pragma unroll
    for (int h = 0; h < 2; ++h) { a0[kt][h] = zf; a1[kt][h] = zf; }
  float h0c[4] = {0.f, 0.f, 0.f, 0.f};
  float h1c[4] = {0.f, 0.f, 0.f, 0.f};

  __syncthreads();

#define MF(acc, A, B) acc = __builtin_amdgcn_mfma_f32_16x16x32_bf16(A, B, acc, 0, 0, 0)
#define MF3(acc, Af, Bf) do { \
    MF(acc, Af[0], Bf[0]); MF(acc, Af[0], Bf[1]); MF(acc, Af[1], Bf[0]); } while (0)

  for (int p = 0; p <= TS; ++p) {
    const bool doL0 = (p < TS);
    const bool doL1 = (p >= 1);
    const int par = p & 1;
    f32x4 aR, aZ, aN;
    float xn0[4];
    if (doL0) {
#pragma unroll
      for (int i = 0; i < 4; ++i) {
        const int row = 4 * lg + i;
        const float* xb = &xldsT[p][row][0];
        float4 x4 = *(const float4*)xb;      // broadcast within 16-lane groups
        float2 x2 = *(const float2*)(xb + 4);
        float sr = bi0r, sz = bi0z, sn = bi0n;
        sr = fmaf(wih0g[0][0], x4.x, sr); sz = fmaf(wih0g[1][0], x4.x, sz); sn = fmaf(wih0g[2][0], x4.x, sn);
        sr = fmaf(wih0g[0][1], x4.y, sr); sz = fmaf(wih0g[1][1], x4.y, sz); sn = fmaf(wih0g[2][1], x4.y, sn);
        sr = fmaf(wih0g[0][2], x4.z, sr); sz = fmaf(wih0g[1][2], x4.z, sz); sn = fmaf(wih0g[2][2], x4.z, sn);
        sr = fmaf(wih0g[0][3], x4.w, sr); sz = fmaf(wih0g[1][3], x4.w, sz); sn = fmaf(wih0g[2][3], x4.w, sn);
        sr = fmaf(wih0g[0][4], x2.x, sr); sz = fmaf(wih0g[1][4], x2.x, sz); sn = fmaf(wih0g[2][4], x2.x, sn);
        sr = fmaf(wih0g[0][5], x2.y, sr); sz = fmaf(wih0g[1][5], x2.y, sz); sn = fmaf(wih0g[2][5], x2.y, sn);
        aR[i] = sr + bh0r;
        aZ[i] = sz + bh0z;
        aN[i] = bh0n;
        xn0[i] = sn;
      }
#pragma unroll
      for (int kt = 0; kt < 2; ++kt) {
        MF3(aR, a0[kt], wB[0][0][kt]);
        MF3(aZ, a0[kt], wB[0][1][kt]);
        MF3(aN, a0[kt], wB[0][2][kt]);
      }
    }
    f32x4 R1, Z1, XN, HN;
    if (doL1) {
#pragma unroll
      for (int i = 0; i < 4; ++i) { R1[i] = c1R; Z1[i] = c1Z; XN[i] = b1xn; HN[i] = b1hn; }
#pragma unroll
      for (int kt = 0; kt < 2; ++kt) {
        MF3(R1, a0[kt], wB[1][0][kt]);   // xp1 = h0(p-1) @ Wih1^T
        MF3(Z1, a0[kt], wB[1][1][kt]);
        MF3(XN, a0[kt], wB[1][2][kt]);
        MF3(R1, a1[kt], wB[2][0][kt]);   // h1(p-2) @ Whh1^T
        MF3(Z1, a1[kt], wB[2][1][kt]);
        MF3(HN, a1[kt], wB[2][2][kt]);
      }
    }
    if (doL0) {
#pragma unroll
      for (int i = 0; i < 4; ++i) {
        float r = sigf(aR[i]);
        float z = sigf(aZ[i]);
        float n = tanhfast(xn0[i] + r * aN[i]);
        h0c[i] = n + z * (h0c[i] - n);
        // producer-side split: hi=trunc, lo=bf16(v-hi)
        const int row = 4 * lg + i;
        unsigned u = __float_as_uint(h0c[i]);
        h0hiL[par][row][unit] = (unsigned short)(u >> 16);
        float lo = h0c[i] - __uint_as_float(u & 0xffff0000u);
        h0loL[par][row][unit] = (unsigned short)(__float_as_uint(lo) >> 16);
      }
    }
    if (doL1) {
#pragma unroll
      for (int i = 0; i < 4; ++i) {
        float r = sigf(R1[i]);
        float z = sigf(Z1[i]);
        float n = tanhfast(XN[i] + r * HN[i]);
        h1c[i] = n + z * (h1c[i] - n);
      }
      if (p < TS) {
#pragma unroll
        for (int i = 0; i < 4; ++i) {
          const int row = 4 * lg + i;
          unsigned u = __float_as_uint(h1c[i]);
          h1hiL[par][row][unit] = (unsigned short)(u >> 16);
          float lo = h1c[i] - __uint_as_float(u & 0xffff0000u);
          h1loL[par][row][unit] = (unsigned short)(__float_as_uint(lo) >> 16);
        }
      }
    }
    __syncthreads();
    if (p < TS) {
#pragma unroll
      for (int kt = 0; kt < 2; ++kt) {
        const int cb = kt * 32 + 8 * lg;
        bf4_t u0 = *(const bf4_t*)&h0hiL[par][lm][cb];
        bf4_t u1 = *(const bf4_t*)&h0hiL[par][lm][cb + 4];
        a0[kt][0] = __builtin_shufflevector(u0, u1, 0, 1, 2, 3, 4, 5, 6, 7);
        bf4_t l0 = *(const bf4_t*)&h0loL[par][lm][cb];
        bf4_t l1 = *(const bf4_t*)&h0loL[par][lm][cb + 4];
        a0[kt][1] = __builtin_shufflevector(l0, l1, 0, 1, 2, 3, 4, 5, 6, 7);
      }
      if (p >= 1) {
#pragma unroll
        for (int kt = 0; kt < 2; ++kt) {
          const int cb = kt * 32 + 8 * lg;
          bf4_t u0 = *(const bf4_t*)&h1hiL[par][lm][cb];
          bf4_t u1 = *(const bf4_t*)&h1hiL[par][lm][cb + 4];
          a1[kt][0] = __builtin_shufflevector(u0, u1, 0, 1, 2, 3, 4, 5, 6, 7);
          bf4_t l0 = *(const bf4_t*)&h1loL[par][lm][cb];
          bf4_t l1 = *(const bf4_t*)&h1loL[par][lm][cb + 4];
          a1[kt][1] = __builtin_shufflevector(l0, l1, 0, 1, 2, 3, 4, 5, 6, 7);
        }
      }
    }
  }
#undef MF3
#undef MF

#pragma unroll
  for (int i = 0; i < 4; ++i)
    xh_out[(size_t)(r0 + 4 * lg + i) * HD + unit] = h1c[i];

  const float WaU = Wac[unit], WcU = Wac[64 + unit];
#pragma unroll
  for (int i = 0; i < 4; ++i) {
    float av = h1c[i] * WaU, cv = h1c[i] * WcU;
#pragma unroll
    for (int off = 1; off < 16; off <<= 1) {
      av += __shfl_xor(av, off, 64);
      cv += __shfl_xor(cv, off, 64);
    }
    if (lm == 0) {
      red[0][w][4 * lg + i] = av;
      red[1][w][4 * lg + i] = cv;
    }
  }
  __syncthreads();
  if (tid < MB) {
    a_out[r0 + tid] = red[0][0][tid] + red[0][1][tid] + red[0][2][tid] + red[0][3][tid];
    c_out[r0 + tid] = red[1][0][tid] + red[1][1][tid] + red[1][2][tid] + red[1][3][tid];
  }
}

// ---------------------------------------------------------------------------
// Kernel 2a: attention PARTIAL (flash-decoding j-split, runtime nsplit 8 or 4).
// Block (ib, js): rows ib*8..+8, j in [js*jsl, min(NR,(js+1)*jsl)).
// Writes per row: {m, s, acc[64]}.
// ---------------------------------------------------------------------------
__global__ __launch_bounds__(256) void attn_part(
    const float* __restrict__ rel,
    const float* __restrict__ xh,
    const float* __restrict__ aArr, const float* __restrict__ cArr,
    const float* __restrict__ bSc,
    float* __restrict__ part, int jsl, int lsp) {
  __shared__ float xhl[64][68];
  __shared__ float pbuf[8][64];
  __shared__ float cls[1024];

  const int tid = threadIdx.x;
  const int il = tid >> 5;
  const int tk = tid & 31;
  const int bx = blockIdx.x;
  const int ib = bx >> lsp;
  const int js = bx & ((1 << lsp) - 1);
  const int i = ib * 8 + il;
  const int jbeg = js * jsl;
  const int jend = (jbeg + jsl < NR) ? (jbeg + jsl) : NR;
  const int nch = (jend - jbeg + 63) >> 6;
  const float aib = aArr[i] + bSc[0];

  for (int t = tid; t < jsl; t += 256)
    cls[t] = (jbeg + t < NR) ? cArr[jbeg + t] : 0.f;

  float pr[6];
  {
    const float* rp = rel + (size_t)i * (3 * NR) + (size_t)(jbeg + 2 * tk) * 3;
#pragma unroll
    for (int e = 0; e < 6; ++e) pr[e] = rp[e];
  }

  float m = -3.0e38f, s = 0.f, acc0 = 0.f, acc1 = 0.f;

  for (int c = 0; c < nch; ++c) {
    const int j0 = jbeg + c * 64;
    __syncthreads();
    {
      const int jj = tid >> 2, seg = tid & 3;
      const int j = j0 + jj;
      if (j < NR) {
        const float4* src = (const float4*)(xh + (size_t)j * 64 + seg * 16);
#pragma unroll
        for (int q = 0; q < 4; ++q) *(float4*)&xhl[jj][seg * 16 + 4 * q] = src[q];
      } else {
        float4 z = {0.f, 0.f, 0.f, 0.f};
#pragma unroll
        for (int q = 0; q < 4; ++q) *(float4*)&xhl[jj][seg * 16 + 4 * q] = z;
      }
    }

    const int jb = j0 + 2 * tk;
    const bool ok = (jb < jend);
    const int ci = c * 64 + 2 * tk;
    const float cl0 = cls[ci], cl1 = cls[ci + 1];
    float msum0 = pr[0] + pr[1] + pr[2];
    float msum1 = pr[3] + pr[4] + pr[5];
    float w0 = aib + cl0, w1 = aib + cl1;
    w0 = (w0 > 0.f) ? w0 : 0.01f * w0;
    w1 = (w1 > 0.f) ? w1 : 0.01f * w1;
    float vwa0 = (!ok) ? -3.0e37f : ((msum0 == 0.f) ? -1.0e6f : msum0 * w0);
    float vwa1 = (!ok) ? -3.0e37f : ((msum1 == 0.f) ? -1.0e6f : msum1 * w1);

    if (c + 1 < nch) {
      const int jn = j0 + 64 + 2 * tk;
      if (jn < jend) {
        const float* rp = rel + (size_t)i * (3 * NR) + (size_t)jn * 3;
#pragma unroll
        for (int e = 0; e < 6; ++e) pr[e] = rp[e];
      }
    }

    float lm2 = fmaxf(vwa0, vwa1);
#pragma unroll
    for (int off = 16; off; off >>= 1) lm2 = fmaxf(lm2, __shfl_xor(lm2, off, 32));
    const float mn = fmaxf(m, lm2);
    const float f = __expf(m - mn);
    const float p0 = __expf(vwa0 - mn);
    const float p1 = __expf(vwa1 - mn);
    float ls = p0 + p1;
#pragma unroll
    for (int off = 16; off; off >>= 1) ls += __shfl_xor(ls, off, 32);
    s = s * f + ls;
    acc0 *= f;
    acc1 *= f;
    m = mn;
    pbuf[il][2 * tk] = p0;
    pbuf[il][2 * tk + 1] = p1;

    __syncthreads();

#pragma unroll 4
    for (int j4 = 0; j4 < 16; ++j4) {
      float4 pv = *(const float4*)&pbuf[il][4 * j4];
      float2 x0 = *(const float2*)&xhl[4 * j4 + 0][2 * tk];
      float2 x1 = *(const float2*)&xhl[4 * j4 + 1][2 * tk];
      float2 x2 = *(const float2*)&xhl[4 * j4 + 2][2 * tk];
      float2 x3 = *(const float2*)&xhl[4 * j4 + 3][2 * tk];
      acc0 = fmaf(pv.x, x0.x, acc0); acc1 = fmaf(pv.x, x0.y, acc1);
      acc0 = fmaf(pv.y, x1.x, acc0); acc1 = fmaf(pv.y, x1.y, acc1);
      acc0 = fmaf(pv.z, x2.x, acc0); acc1 = fmaf(pv.z, x2.y, acc1);
      acc0 = fmaf(pv.w, x3.x, acc0); acc1 = fmaf(pv.w, x3.y, acc1);
    }
  }

  float* base = part + ((size_t)bx * 8 + il) * 66;
  if (tk == 0) { base[0] = m; base[1] = s; }
  base[2 + 2 * tk] = acc0;
  base[3 + 2 * tk] = acc1;
}

// ---------------------------------------------------------------------------
// Kernel 2b: combine partials + final FC. 1000 blocks x 256 (4 rows/block).
// Re-reads part (L2-hot) instead of register arrays (avoid dynamic indexing).
// ---------------------------------------------------------------------------
__global__ __launch_bounds__(256) void attn_combine(
    const float* __restrict__ part,
    const float* __restrict__ xh,
    const float* __restrict__ fcw, const float* __restrict__ fcb,
    float* __restrict__ pred, int nsplit) {
  const int tid = threadIdx.x;
  const int r = blockIdx.x * 4 + (tid >> 6);
  const int lane = tid & 63;
  const int ib = r >> 3, il = r & 7;

  float mstar = -3.0e38f;
  for (int k = 0; k < nsplit; ++k) {
    const float* b = part + ((size_t)(ib * nsplit + k) * 8 + il) * 66;
    mstar = fmaxf(mstar, b[0]);
  }
  float sstar = 0.f, onum = 0.f;
  for (int k = 0; k < nsplit; ++k) {
    const float* b = part + ((size_t)(ib * nsplit + k) * 8 + il) * 66;
    const float wk = __expf(b[0] - mstar);
    sstar = fmaf(wk, b[1], sstar);
    onum = fmaf(wk, b[2 + lane], onum);
  }
  const float o = onum / sstar;
  float p = fcw[lane] * xh[(size_t)r * HD + lane] + fcw[64 + lane] * o;
#pragma unroll
  for (int off = 32; off; off >>= 1) p += __shfl_xor(p, off, 64);
  if (lane == 0) pred[r] = p + fcb[0];
}

extern "C" void kernel_launch(void* const* d_in, const int* in_sizes, int n_in,
                              void* d_out, int out_size, void* d_ws, size_t ws_size,
                              hipStream_t stream) {
  const float* x    = (const float*)d_in[0];
  const float* rel  = (const float*)d_in[1];
  const float* Wih0 = (const float*)d_in[2];
  const float* Whh0 = (const float*)d_in[3];
  const float* bih0 = (const float*)d_in[4];
  const float* bhh0 = (const float*)d_in[5];
  const float* Wih1 = (const float*)d_in[6];
  const float* Whh1 = (const float*)d_in[7];
  const float* bih1 = (const float*)d_in[8];
  const float* bhh1 = (const float*)d_in[9];
  const float* Wac  = (const float*)d_in[10];
  const float* bSc  = (const float*)d_in[11];
  const float* fcw  = (const float*)d_in[12];
  const float* fcb  = (const float*)d_in[13];

  float* xh   = (float*)d_ws;
  float* aA   = xh + (size_t)NR * HD;
  float* cA   = aA + NR;
  float* part = cA + NR;
  float* pred = (float*)d_out;

  // nsplit=8 needs ~9.5MB ws; fall back to round-7-proven nsplit=4 (5.3MB)
  int nsplit = 8, lsp = 3;
  size_t needB = ((size_t)NR * HD + 2 * NR + (size_t)500 * 8 * 8 * 66) * 4;
  if (ws_size < needB) { nsplit = 4; lsp = 2; }
  const int jsl = NR / nsplit;

  gru_mfma<<<NR / MB, 256, 0, stream>>>(x, Wih0, Whh0, bih0, bhh0, Wih1, Whh1,
                                        bih1, bhh1, Wac, xh, aA, cA);
  attn_part<<<(NR / 8) * nsplit, 256, 0, stream>>>(rel, xh, aA, cA, bSc, part, jsl, lsp);
  attn_combine<<<NR / 4, 256, 0, stream>>>(part, xh, fcw, fcb, pred, nsplit);
}

// Round 9
// 180.695 us; speedup vs baseline: 4.4544x; 1.2534x over previous
//
#include <hip/hip_runtime.h>

#define NR 4000
#define TS 60
#define DF 6
#define HD 64
#define MB 16    // rows per GRU block
#define ARB 32   // rows per attn block

typedef __attribute__((ext_vector_type(8))) short bf8_t;
typedef __attribute__((ext_vector_type(4))) short bf4_t;
typedef __attribute__((ext_vector_type(4))) float f32x4;

__device__ __forceinline__ float sigf(float x) { return 1.0f / (1.0f + __expf(-x)); }
__device__ __forceinline__ float tanhfast(float x) { return 1.0f - 2.0f / (1.0f + __expf(2.0f * x)); }

__device__ __forceinline__ unsigned short f2bf(float v) {  // RTN (weights, one-time)
  union { float f; unsigned u; } x; x.f = v;
  unsigned r = (x.u + 0x7fffu + ((x.u >> 16) & 1u)) >> 16;
  return (unsigned short)r;
}
__device__ __forceinline__ float bf2f(unsigned short h) {
  union { unsigned u; float f; } y; y.u = ((unsigned)h) << 16; return y.f;
}
__device__ __forceinline__ void split8(const float* v, bf8_t& hi, bf8_t& lo) {
#pragma unroll
  for (int j = 0; j < 8; ++j) {
    unsigned short h = f2bf(v[j]);
    float rem = v[j] - bf2f(h);
    hi[j] = (short)h;
    lo[j] = (short)f2bf(rem);
  }
}

// ---------------------------------------------------------------------------
// Kernel 1: fused 2-layer GRU via split-bf16 MFMA (unchanged from round 8:
// 250 blocks x 16 rows, 4 waves, skewed single-barrier phases, producer-side
// hi/lo split, consumer raw ds_read frags). ~93us, latency-bound.
// ---------------------------------------------------------------------------
__global__ __launch_bounds__(256, 1) void gru_mfma(
    const float* __restrict__ x,
    const float* __restrict__ Wih0, const float* __restrict__ Whh0,
    const float* __restrict__ bih0, const float* __restrict__ bhh0,
    const float* __restrict__ Wih1, const float* __restrict__ Whh1,
    const float* __restrict__ bih1, const float* __restrict__ bhh1,
    const float* __restrict__ Wac,
    float* __restrict__ xh_out, float* __restrict__ a_out, float* __restrict__ c_out) {
  __shared__ float xldsT[TS][MB][12];
  __shared__ unsigned short h0hiL[2][16][76];
  __shared__ unsigned short h0loL[2][16][76];
  __shared__ unsigned short h1hiL[2][16][76];
  __shared__ unsigned short h1loL[2][16][76];
  __shared__ float red[2][4][MB];

  const int tid = threadIdx.x;
  const int w = tid >> 6;
  const int lane = tid & 63;
  const int lg = lane >> 4;
  const int lm = lane & 15;
  const int unit = w * 16 + lm;
  const int r0 = blockIdx.x * MB;

  for (int idx = tid; idx < MB * 360; idx += 256) {
    int rr = idx / 360, cc = idx - rr * 360;
    int f = cc / 60, t = cc - f * 60;
    xldsT[t][rr][f] = x[(size_t)r0 * 360 + idx];
  }

  bf8_t wB[3][3][2][2];
  {
    const float* mats[3] = {Whh0, Wih1, Whh1};
#pragma unroll
    for (int m = 0; m < 3; ++m)
#pragma unroll
      for (int g = 0; g < 3; ++g)
#pragma unroll
        for (int kt = 0; kt < 2; ++kt) {
          const float* src = mats[m] + (size_t)(g * 64 + unit) * 64 + kt * 32 + 8 * lg;
          float v[8];
          *(float4*)&v[0] = *(const float4*)&src[0];
          *(float4*)&v[4] = *(const float4*)&src[4];
          split8(v, wB[m][g][kt][0], wB[m][g][kt][1]);
        }
  }
  float wih0g[3][DF];
#pragma unroll
  for (int g = 0; g < 3; ++g)
#pragma unroll
    for (int f = 0; f < DF; ++f)
      wih0g[g][f] = Wih0[(size_t)(g * 64 + unit) * DF + f];

  const float bi0r = bih0[unit], bi0z = bih0[64 + unit], bi0n = bih0[128 + unit];
  const float bh0r = bhh0[unit], bh0z = bhh0[64 + unit], bh0n = bhh0[128 + unit];
  const float c1R = bih1[unit] + bhh1[unit];
  const float c1Z = bih1[64 + unit] + bhh1[64 + unit];
  const float b1xn = bih1[128 + unit], b1hn = bhh1[128 + unit];

  bf8_t a0[2][2], a1[2][2];
  bf8_t zf = {};
#pragma unroll
  for (int kt = 0; kt < 2; ++kt)
#pragma unroll
    for (int h = 0; h < 2; ++h) { a0[kt][h] = zf; a1[kt][h] = zf; }
  float h0c[4] = {0.f, 0.f, 0.f, 0.f};
  float h1c[4] = {0.f, 0.f, 0.f, 0.f};

  __syncthreads();

#define MF(acc, A, B) acc = __builtin_amdgcn_mfma_f32_16x16x32_bf16(A, B, acc, 0, 0, 0)
#define MF3(acc, Af, Bf) do { \
    MF(acc, Af[0], Bf[0]); MF(acc, Af[0], Bf[1]); MF(acc, Af[1], Bf[0]); } while (0)

  for (int p = 0; p <= TS; ++p) {
    const bool doL0 = (p < TS);
    const bool doL1 = (p >= 1);
    const int par = p & 1;
    f32x4 aR, aZ, aN;
    float xn0[4];
    if (doL0) {
#pragma unroll
      for (int i = 0; i < 4; ++i) {
        const int row = 4 * lg + i;
        const float* xb = &xldsT[p][row][0];
        float4 x4 = *(const float4*)xb;
        float2 x2 = *(const float2*)(xb + 4);
        float sr = bi0r, sz = bi0z, sn = bi0n;
        sr = fmaf(wih0g[0][0], x4.x, sr); sz = fmaf(wih0g[1][0], x4.x, sz); sn = fmaf(wih0g[2][0], x4.x, sn);
        sr = fmaf(wih0g[0][1], x4.y, sr); sz = fmaf(wih0g[1][1], x4.y, sz); sn = fmaf(wih0g[2][1], x4.y, sn);
        sr = fmaf(wih0g[0][2], x4.z, sr); sz = fmaf(wih0g[1][2], x4.z, sz); sn = fmaf(wih0g[2][2], x4.z, sn);
        sr = fmaf(wih0g[0][3], x4.w, sr); sz = fmaf(wih0g[1][3], x4.w, sz); sn = fmaf(wih0g[2][3], x4.w, sn);
        sr = fmaf(wih0g[0][4], x2.x, sr); sz = fmaf(wih0g[1][4], x2.x, sz); sn = fmaf(wih0g[2][4], x2.x, sn);
        sr = fmaf(wih0g[0][5], x2.y, sr); sz = fmaf(wih0g[1][5], x2.y, sz); sn = fmaf(wih0g[2][5], x2.y, sn);
        aR[i] = sr + bh0r;
        aZ[i] = sz + bh0z;
        aN[i] = bh0n;
        xn0[i] = sn;
      }
#pragma unroll
      for (int kt = 0; kt < 2; ++kt) {
        MF3(aR, a0[kt], wB[0][0][kt]);
        MF3(aZ, a0[kt], wB[0][1][kt]);
        MF3(aN, a0[kt], wB[0][2][kt]);
      }
    }
    f32x4 R1, Z1, XN, HN;
    if (doL1) {
#pragma unroll
      for (int i = 0; i < 4; ++i) { R1[i] = c1R; Z1[i] = c1Z; XN[i] = b1xn; HN[i] = b1hn; }
#pragma unroll
      for (int kt = 0; kt < 2; ++kt) {
        MF3(R1, a0[kt], wB[1][0][kt]);
        MF3(Z1, a0[kt], wB[1][1][kt]);
        MF3(XN, a0[kt], wB[1][2][kt]);
        MF3(R1, a1[kt], wB[2][0][kt]);
        MF3(Z1, a1[kt], wB[2][1][kt]);
        MF3(HN, a1[kt], wB[2][2][kt]);
      }
    }
    if (doL0) {
#pragma unroll
      for (int i = 0; i < 4; ++i) {
        float r = sigf(aR[i]);
        float z = sigf(aZ[i]);
        float n = tanhfast(xn0[i] + r * aN[i]);
        h0c[i] = n + z * (h0c[i] - n);
        const int row = 4 * lg + i;
        unsigned u = __float_as_uint(h0c[i]);
        h0hiL[par][row][unit] = (unsigned short)(u >> 16);
        float lo = h0c[i] - __uint_as_float(u & 0xffff0000u);
        h0loL[par][row][unit] = (unsigned short)(__float_as_uint(lo) >> 16);
      }
    }
    if (doL1) {
#pragma unroll
      for (int i = 0; i < 4; ++i) {
        float r = sigf(R1[i]);
        float z = sigf(Z1[i]);
        float n = tanhfast(XN[i] + r * HN[i]);
        h1c[i] = n + z * (h1c[i] - n);
      }
      if (p < TS) {
#pragma unroll
        for (int i = 0; i < 4; ++i) {
          const int row = 4 * lg + i;
          unsigned u = __float_as_uint(h1c[i]);
          h1hiL[par][row][unit] = (unsigned short)(u >> 16);
          float lo = h1c[i] - __uint_as_float(u & 0xffff0000u);
          h1loL[par][row][unit] = (unsigned short)(__float_as_uint(lo) >> 16);
        }
      }
    }
    __syncthreads();
    if (p < TS) {
#pragma unroll
      for (int kt = 0; kt < 2; ++kt) {
        const int cb = kt * 32 + 8 * lg;
        bf4_t u0 = *(const bf4_t*)&h0hiL[par][lm][cb];
        bf4_t u1 = *(const bf4_t*)&h0hiL[par][lm][cb + 4];
        a0[kt][0] = __builtin_shufflevector(u0, u1, 0, 1, 2, 3, 4, 5, 6, 7);
        bf4_t l0 = *(const bf4_t*)&h0loL[par][lm][cb];
        bf4_t l1 = *(const bf4_t*)&h0loL[par][lm][cb + 4];
        a0[kt][1] = __builtin_shufflevector(l0, l1, 0, 1, 2, 3, 4, 5, 6, 7);
      }
      if (p >= 1) {
#pragma unroll
        for (int kt = 0; kt < 2; ++kt) {
          const int cb = kt * 32 + 8 * lg;
          bf4_t u0 = *(const bf4_t*)&h1hiL[par][lm][cb];
          bf4_t u1 = *(const bf4_t*)&h1hiL[par][lm][cb + 4];
          a1[kt][0] = __builtin_shufflevector(u0, u1, 0, 1, 2, 3, 4, 5, 6, 7);
          bf4_t l0 = *(const bf4_t*)&h1loL[par][lm][cb];
          bf4_t l1 = *(const bf4_t*)&h1loL[par][lm][cb + 4];
          a1[kt][1] = __builtin_shufflevector(l0, l1, 0, 1, 2, 3, 4, 5, 6, 7);
        }
      }
    }
  }
#undef MF3
#undef MF

#pragma unroll
  for (int i = 0; i < 4; ++i)
    xh_out[(size_t)(r0 + 4 * lg + i) * HD + unit] = h1c[i];

  const float WaU = Wac[unit], WcU = Wac[64 + unit];
#pragma unroll
  for (int i = 0; i < 4; ++i) {
    float av = h1c[i] * WaU, cv = h1c[i] * WcU;
#pragma unroll
    for (int off = 1; off < 16; off <<= 1) {
      av += __shfl_xor(av, off, 64);
      cv += __shfl_xor(cv, off, 64);
    }
    if (lm == 0) {
      red[0][w][4 * lg + i] = av;
      red[1][w][4 * lg + i] = cv;
    }
  }
  __syncthreads();
  if (tid < MB) {
    a_out[r0 + tid] = red[0][0][tid] + red[0][1][tid] + red[0][2][tid] + red[0][3][tid];
    c_out[r0 + tid] = red[1][0][tid] + red[1][1][tid] + red[1][2][tid] + red[1][3][tid];
  }
}

// ---------------------------------------------------------------------------
// Kernel 2a: attention PARTIAL, 32 rows/block x 4 rows/thread.
// Thread (rg=tid>>5, tk=tid&31) owns rows {rg, rg+8, rg+16, rg+24} x cols
// {2tk, 2tk+1}: each xhl LDS read feeds 4 rows (4x LDS-BW cut vs round 8,
// which was LDS-read-bound at ~61us of 128us).
// Grid: (NR/32) * nsplit blocks; j-slice [js*jsl, ...).
// ---------------------------------------------------------------------------
__global__ __launch_bounds__(256) void attn_part(
    const float* __restrict__ rel,
    const float* __restrict__ xh,
    const float* __restrict__ aArr, const float* __restrict__ cArr,
    const float* __restrict__ bSc,
    float* __restrict__ part, int jsl, int lsp) {
  __shared__ float xhl[64][68];
  __shared__ float pbuf[ARB][64];
  __shared__ float cls[1024];

  const int tid = threadIdx.x;
  const int rg = tid >> 5;
  const int tk = tid & 31;
  const int bx = blockIdx.x;
  const int ib = bx >> lsp;
  const int js = bx & ((1 << lsp) - 1);
  const int jbeg = js * jsl;
  const int jend = (jbeg + jsl < NR) ? (jbeg + jsl) : NR;
  const int nch = (jend - jbeg + 63) >> 6;
  const float bb = bSc[0];

  int irow[4];
  float aib[4];
#pragma unroll
  for (int rr = 0; rr < 4; ++rr) {
    irow[rr] = ib * ARB + rg + 8 * rr;
    aib[rr] = aArr[irow[rr]] + bb;
  }

  for (int t = tid; t < jsl; t += 256)
    cls[t] = (jbeg + t < NR) ? cArr[jbeg + t] : 0.f;

  float pr[4][6];
#pragma unroll
  for (int rr = 0; rr < 4; ++rr) {
    const float* rp = rel + (size_t)irow[rr] * (3 * NR) + (size_t)(jbeg + 2 * tk) * 3;
#pragma unroll
    for (int e = 0; e < 6; ++e) pr[rr][e] = rp[e];
  }

  float m[4], s[4], acc0[4], acc1[4];
#pragma unroll
  for (int rr = 0; rr < 4; ++rr) { m[rr] = -3.0e38f; s[rr] = 0.f; acc0[rr] = 0.f; acc1[rr] = 0.f; }

  for (int c = 0; c < nch; ++c) {
    const int j0 = jbeg + c * 64;
    __syncthreads();
    // stage xh chunk (64 rows x 64 cols, padded 68)
    {
      const int jj = tid >> 2, seg = tid & 3;
      const int j = j0 + jj;
      if (j < NR) {
        const float4* src = (const float4*)(xh + (size_t)j * 64 + seg * 16);
#pragma unroll
        for (int q = 0; q < 4; ++q) *(float4*)&xhl[jj][seg * 16 + 4 * q] = src[q];
      } else {
        float4 z = {0.f, 0.f, 0.f, 0.f};
#pragma unroll
        for (int q = 0; q < 4; ++q) *(float4*)&xhl[jj][seg * 16 + 4 * q] = z;
      }
    }

    const int jb = j0 + 2 * tk;
    const bool ok = (jb < jend);
    const int ci = c * 64 + 2 * tk;
    const float cl0 = cls[ci], cl1 = cls[ci + 1];

#pragma unroll
    for (int rr = 0; rr < 4; ++rr) {
      float msum0 = pr[rr][0] + pr[rr][1] + pr[rr][2];
      float msum1 = pr[rr][3] + pr[rr][4] + pr[rr][5];
      float w0 = aib[rr] + cl0, w1 = aib[rr] + cl1;
      w0 = (w0 > 0.f) ? w0 : 0.01f * w0;
      w1 = (w1 > 0.f) ? w1 : 0.01f * w1;
      float v0 = (!ok) ? -3.0e37f : ((msum0 == 0.f) ? -1.0e6f : msum0 * w0);
      float v1 = (!ok) ? -3.0e37f : ((msum1 == 0.f) ? -1.0e6f : msum1 * w1);

      float lm2 = fmaxf(v0, v1);
#pragma unroll
      for (int off = 16; off; off >>= 1) lm2 = fmaxf(lm2, __shfl_xor(lm2, off, 32));
      const float mn = fmaxf(m[rr], lm2);
      const float f = __expf(m[rr] - mn);
      const float p0 = __expf(v0 - mn);
      const float p1 = __expf(v1 - mn);
      float ls = p0 + p1;
#pragma unroll
      for (int off = 16; off; off >>= 1) ls += __shfl_xor(ls, off, 32);
      s[rr] = s[rr] * f + ls;
      acc0[rr] *= f;
      acc1[rr] *= f;
      m[rr] = mn;
      pbuf[rg + 8 * rr][2 * tk] = p0;
      pbuf[rg + 8 * rr][2 * tk + 1] = p1;  // same half-wave writes & reads
    }

    // prefetch next chunk's rel for all 4 rows
    if (c + 1 < nch) {
      const int jn = j0 + 64 + 2 * tk;
      if (jn < jend) {
#pragma unroll
        for (int rr = 0; rr < 4; ++rr) {
          const float* rp = rel + (size_t)irow[rr] * (3 * NR) + (size_t)jn * 3;
#pragma unroll
          for (int e = 0; e < 6; ++e) pr[rr][e] = rp[e];
        }
      }
    }

    __syncthreads();  // xhl ready

#pragma unroll 2
    for (int j4 = 0; j4 < 16; ++j4) {
      float4 pv0 = *(const float4*)&pbuf[rg][4 * j4];
      float4 pv1 = *(const float4*)&pbuf[rg + 8][4 * j4];
      float4 pv2 = *(const float4*)&pbuf[rg + 16][4 * j4];
      float4 pv3 = *(const float4*)&pbuf[rg + 24][4 * j4];
      float2 x0 = *(const float2*)&xhl[4 * j4 + 0][2 * tk];
      float2 x1 = *(const float2*)&xhl[4 * j4 + 1][2 * tk];
      float2 x2 = *(const float2*)&xhl[4 * j4 + 2][2 * tk];
      float2 x3 = *(const float2*)&xhl[4 * j4 + 3][2 * tk];
      acc0[0] = fmaf(pv0.x, x0.x, acc0[0]); acc1[0] = fmaf(pv0.x, x0.y, acc1[0]);
      acc0[0] = fmaf(pv0.y, x1.x, acc0[0]); acc1[0] = fmaf(pv0.y, x1.y, acc1[0]);
      acc0[0] = fmaf(pv0.z, x2.x, acc0[0]); acc1[0] = fmaf(pv0.z, x2.y, acc1[0]);
      acc0[0] = fmaf(pv0.w, x3.x, acc0[0]); acc1[0] = fmaf(pv0.w, x3.y, acc1[0]);
      acc0[1] = fmaf(pv1.x, x0.x, acc0[1]); acc1[1] = fmaf(pv1.x, x0.y, acc1[1]);
      acc0[1] = fmaf(pv1.y, x1.x, acc0[1]); acc1[1] = fmaf(pv1.y, x1.y, acc1[1]);
      acc0[1] = fmaf(pv1.z, x2.x, acc0[1]); acc1[1] = fmaf(pv1.z, x2.y, acc1[1]);
      acc0[1] = fmaf(pv1.w, x3.x, acc0[1]); acc1[1] = fmaf(pv1.w, x3.y, acc1[1]);
      acc0[2] = fmaf(pv2.x, x0.x, acc0[2]); acc1[2] = fmaf(pv2.x, x0.y, acc1[2]);
      acc0[2] = fmaf(pv2.y, x1.x, acc0[2]); acc1[2] = fmaf(pv2.y, x1.y, acc1[2]);
      acc0[2] = fmaf(pv2.z, x2.x, acc0[2]); acc1[2] = fmaf(pv2.z, x2.y, acc1[2]);
      acc0[2] = fmaf(pv2.w, x3.x, acc0[2]); acc1[2] = fmaf(pv2.w, x3.y, acc1[2]);
      acc0[3] = fmaf(pv3.x, x0.x, acc0[3]); acc1[3] = fmaf(pv3.x, x0.y, acc1[3]);
      acc0[3] = fmaf(pv3.y, x1.x, acc0[3]); acc1[3] = fmaf(pv3.y, x1.y, acc1[3]);
      acc0[3] = fmaf(pv3.z, x2.x, acc0[3]); acc1[3] = fmaf(pv3.z, x2.y, acc1[3]);
      acc0[3] = fmaf(pv3.w, x3.x, acc0[3]); acc1[3] = fmaf(pv3.w, x3.y, acc1[3]);
    }
  }

#pragma unroll
  for (int rr = 0; rr < 4; ++rr) {
    float* base = part + ((size_t)bx * ARB + rg + 8 * rr) * 66;
    if (tk == 0) { base[0] = m[rr]; base[1] = s[rr]; }
    base[2 + 2 * tk] = acc0[rr];
    base[3 + 2 * tk] = acc1[rr];
  }
}

// ---------------------------------------------------------------------------
// Kernel 2b: combine partials + final FC. NR/4 blocks x 256 (4 rows/block).
// ---------------------------------------------------------------------------
__global__ __launch_bounds__(256) void attn_combine(
    const float* __restrict__ part,
    const float* __restrict__ xh,
    const float* __restrict__ fcw, const float* __restrict__ fcb,
    float* __restrict__ pred, int nsplit) {
  const int tid = threadIdx.x;
  const int r = blockIdx.x * 4 + (tid >> 6);
  const int lane = tid & 63;
  const int ib = r / ARB, il = r % ARB;

  float mstar = -3.0e38f;
  for (int k = 0; k < nsplit; ++k) {
    const float* b = part + ((size_t)(ib * nsplit + k) * ARB + il) * 66;
    mstar = fmaxf(mstar, b[0]);
  }
  float sstar = 0.f, onum = 0.f;
  for (int k = 0; k < nsplit; ++k) {
    const float* b = part + ((size_t)(ib * nsplit + k) * ARB + il) * 66;
    const float wk = __expf(b[0] - mstar);
    sstar = fmaf(wk, b[1], sstar);
    onum = fmaf(wk, b[2 + lane], onum);
  }
  const float o = onum / sstar;
  float p = fcw[lane] * xh[(size_t)r * HD + lane] + fcw[64 + lane] * o;
#pragma unroll
  for (int off = 32; off; off >>= 1) p += __shfl_xor(p, off, 64);
  if (lane == 0) pred[r] = p + fcb[0];
}

extern "C" void kernel_launch(void* const* d_in, const int* in_sizes, int n_in,
                              void* d_out, int out_size, void* d_ws, size_t ws_size,
                              hipStream_t stream) {
  const float* x    = (const float*)d_in[0];
  const float* rel  = (const float*)d_in[1];
  const float* Wih0 = (const float*)d_in[2];
  const float* Whh0 = (const float*)d_in[3];
  const float* bih0 = (const float*)d_in[4];
  const float* bhh0 = (const float*)d_in[5];
  const float* Wih1 = (const float*)d_in[6];
  const float* Whh1 = (const float*)d_in[7];
  const float* bih1 = (const float*)d_in[8];
  const float* bhh1 = (const float*)d_in[9];
  const float* Wac  = (const float*)d_in[10];
  const float* bSc  = (const float*)d_in[11];
  const float* fcw  = (const float*)d_in[12];
  const float* fcb  = (const float*)d_in[13];

  float* xh   = (float*)d_ws;
  float* aA   = xh + (size_t)NR * HD;
  float* cA   = aA + NR;
  float* part = cA + NR;
  float* pred = (float*)d_out;

  // nsplit=8: part = (125*8 blocks)*32*66 floats = 8.45MB (+1.06MB head).
  // Fallback nsplit=4 if ws too small.
  int nsplit = 8, lsp = 3;
  size_t needB = ((size_t)NR * HD + 2 * NR +
                  (size_t)(NR / ARB) * 8 * ARB * 66) * 4;
  if (ws_size < needB) { nsplit = 4; lsp = 2; }
  const int jsl = NR / nsplit;

  gru_mfma<<<NR / MB, 256, 0, stream>>>(x, Wih0, Whh0, bih0, bhh0, Wih1, Whh1,
                                        bih1, bhh1, Wac, xh, aA, cA);
  attn_part<<<(NR / ARB) * nsplit, 256, 0, stream>>>(rel, xh, aA, cA, bSc, part, jsl, lsp);
  attn_combine<<<NR / 4, 256, 0, stream>>>(part, xh, fcw, fcb, pred, nsplit);
}